// Round 6
// baseline (276.532 us; speedup 1.0000x reference)
//
#include <hip/hip_runtime.h>

typedef _Float16 half_t;
typedef _Float16 half2_t __attribute__((ext_vector_type(2)));

#define BB 4
#define NN 1024
#define NH 8
#define KD 16
#define ID 128
#define ED 128

static constexpr size_t OUT_SZ   = (size_t)BB * NN * ED;       // 524288
static constexpr size_t ATT_SZ   = (size_t)NH * BB * NN * NN;  // 33554432
static constexpr size_t OFF_OSS  = OUT_SZ;
static constexpr size_t OFF_ST   = OUT_SZ + ATT_SZ;
static constexpr size_t HSTRIDE  = (size_t)BB * NN * NN;       // per-head stride in (h,b,n,m)

#define LGW 1032   // f16 elements per logits row (1024 + 8 pad)

__device__ __forceinline__ float fdot2u(unsigned int a, unsigned int b, float c) {
    union { unsigned int u; half2_t h; } ua, ub;
    ua.u = a; ub.u = b;
    return __builtin_amdgcn_fdot2(ua.h, ub.h, c, false);
}

// ---------------- Kernel 1: QKV projection ----------------
// Qh  [ (b*N+n)*128 + h*16+k ]                       (f16, natural k-pair u32 layout)
// Kp  [ ((b*8+h)*8+kp)*N + n ] u32 = (K[n][2kp],K[n][2kp+1])   (k-pair packed along n)
// Vp  [ ((b*8+h)*8+vp)*N + n ] u32 = (V[n][2vp],V[n][2vp+1])   (v-pair packed along n)
__global__ __launch_bounds__(128) void qkv_kernel(
    const float* __restrict__ q,  const float* __restrict__ Wq,
    const float* __restrict__ Wk, const float* __restrict__ Wv,
    half_t* __restrict__ Qh, half_t* __restrict__ Kp, half_t* __restrict__ Vp)
{
    const int bn = blockIdx.x;           // 0..4095
    const int j  = threadIdx.x;          // 0..127 -> (h,k)
    const int h  = j >> 4, k = j & 15;
    const int b  = bn >> 10, n = bn & 1023;

    __shared__ float qrow[ID];
    qrow[j] = q[(size_t)bn * ID + j];
    __syncthreads();

    const float* wq = Wq + h * ID * KD + k;
    const float* wk = Wk + h * ID * KD + k;
    const float* wv = Wv + h * ID * KD + k;
    float aq = 0.f, ak = 0.f, av = 0.f;
#pragma unroll
    for (int i = 0; i < ID; ++i) {
        float x = qrow[i];
        aq = fmaf(x, wq[i * KD], aq);
        ak = fmaf(x, wk[i * KD], ak);
        av = fmaf(x, wv[i * KD], av);
    }
    Qh[(size_t)bn * 128 + j] = (half_t)aq;
    const size_t pr = ((size_t)((b * NH + h) * 8 + (k >> 1)) * NN + n) * 2 + (k & 1);
    Kp[pr] = (half_t)ak;
    Vp[pr] = (half_t)av;
}

// ---------------- Kernel 2: fused logits+MLP+softmax+PV+proj + passthrough ----------------
__global__ __launch_bounds__(256, 8) void fused_kernel(
    const float* __restrict__ oss, const float* __restrict__ st,
    const half_t* __restrict__ Qh, const unsigned int* __restrict__ Kp,
    const unsigned int* __restrict__ Vp,
    const float* __restrict__ w1,  const float* __restrict__ b1,
    const float* __restrict__ w2,  const float* __restrict__ b2,
    const float* __restrict__ Wout, float* __restrict__ out)
{
    const int n   = blockIdx.x;
    const int b   = blockIdx.y;
    const int tid = threadIdx.x;

    __shared__ __align__(16) half_t lg[NH * LGW];   // 16.1 KB f16 logits/weights
    __shared__ unsigned int qsh[64];
    __shared__ float wred[4][8];
    __shared__ float wsum[4][8];
    __shared__ float headsSh[128];

    if (tid < 64) qsh[tid] =
        reinterpret_cast<const unsigned int*>(Qh + ((size_t)(b * NN + n)) * 128)[tid];
    __syncthreads();

    const int m0 = tid * 4;                         // thread owns m0..m0+3
    const size_t bn_off = ((size_t)(b * NN + n)) * NN;

    // layer-1 accumulators, streamed over h
    float y[4][8];
#pragma unroll
    for (int mo = 0; mo < 4; ++mo)
#pragma unroll
        for (int o = 0; o < 8; ++o) y[mo][o] = b1[o];

    // -------- pass A with 1-deep st/oss prefetch --------
    size_t idx_c = bn_off + (size_t)m0;             // h = 0
    float4 sv_c = *reinterpret_cast<const float4*>(st + idx_c);
    float4 ov_c = *reinterpret_cast<const float4*>(oss + idx_c);

#pragma unroll 1
    for (int h = 0; h < 8; ++h) {
        // prefetch next h's streams (clamped on last iter)
        const size_t idx_n = idx_c + (h < 7 ? HSTRIDE : 0);
        const float4 sv_n = *reinterpret_cast<const float4*>(st + idx_n);
        const float4 ov_n = *reinterpret_cast<const float4*>(oss + idx_n);

        // QK^T for 4 m: k-pair packed, coalesced uint4 loads (4 consecutive n)
        const unsigned int* kb = Kp + ((size_t)((b * NH + h) * 8)) * NN + m0;
        float acc[4] = {0.f, 0.f, 0.f, 0.f};
#pragma unroll
        for (int kp = 0; kp < 8; ++kp) {
            const uint4 k4 = *reinterpret_cast<const uint4*>(kb + (size_t)kp * NN);
            const unsigned int qp = qsh[h * 8 + kp];
            acc[0] = fdot2u(k4.x, qp, acc[0]);
            acc[1] = fdot2u(k4.y, qp, acc[1]);
            acc[2] = fdot2u(k4.z, qp, acc[2]);
            acc[3] = fdot2u(k4.w, qp, acc[3]);
        }

        // passthrough stores for current h (data already in regs)
        *reinterpret_cast<float4*>(out + OFF_ST + idx_c)  = sv_c;
        *reinterpret_cast<float4*>(out + OFF_OSS + idx_c) = ov_c;

        const float svv[4] = {sv_c.x, sv_c.y, sv_c.z, sv_c.w};
        const float ovv[4] = {ov_c.x, ov_c.y, ov_c.z, ov_c.w};
        float w1c[8], w1o[8];                       // uniform -> SGPRs
#pragma unroll
        for (int o = 0; o < 8; ++o) { w1c[o] = w1[o * 16 + h]; w1o[o] = w1[o * 16 + 8 + h]; }
#pragma unroll
        for (int mo = 0; mo < 4; ++mo) {
            const float c = (acc[mo] + svv[mo]) * 0.25f;   // (QK + st) * 1/sqrt(16)
#pragma unroll
            for (int o = 0; o < 8; ++o)
                y[mo][o] = fmaf(c, w1c[o], fmaf(ovv[mo], w1o[o], y[mo][o]));
        }
        sv_c = sv_n; ov_c = ov_n; idx_c = idx_n;
    }

    // ---- layer 2 -> f16 logits in LDS + per-thread max ----
    float lgv[8][4];
#pragma unroll
    for (int mo = 0; mo < 4; ++mo) {
        float z[8];
#pragma unroll
        for (int o = 0; o < 8; ++o) z[o] = fmaxf(y[mo][o], 0.f);
#pragma unroll
        for (int p = 0; p < 8; ++p) {
            float a = b2[p];
#pragma unroll
            for (int o = 0; o < 8; ++o) a = fmaf(z[o], w2[p * 8 + o], a);
            lgv[p][mo] = a;
        }
    }
    float tmax[8];
#pragma unroll
    for (int p = 0; p < 8; ++p) {
        union { uint2 u; half_t h4[4]; } pk;
#pragma unroll
        for (int mo = 0; mo < 4; ++mo) pk.h4[mo] = (half_t)lgv[p][mo];
        *reinterpret_cast<uint2*>(&lg[p * LGW + m0]) = pk.u;
        tmax[p] = fmaxf(fmaxf(lgv[p][0], lgv[p][1]), fmaxf(lgv[p][2], lgv[p][3]));
    }
#pragma unroll
    for (int p = 0; p < 8; ++p)
#pragma unroll
        for (int s = 32; s > 0; s >>= 1)
            tmax[p] = fmaxf(tmax[p], __shfl_xor(tmax[p], s));
    const int wv = tid >> 6;
    if ((tid & 63) == 0) {
#pragma unroll
        for (int p = 0; p < 8; ++p) wred[wv][p] = tmax[p];
    }
    __syncthreads();

    float bmax[8];
#pragma unroll
    for (int p = 0; p < 8; ++p)
        bmax[p] = fmaxf(fmaxf(wred[0][p], wred[1][p]), fmaxf(wred[2][p], wred[3][p]));

    // ---- exp in place (f16) + per-thread sums ----
    float psum[8];
#pragma unroll
    for (int p = 0; p < 8; ++p) {
        union { uint2 u; half_t h4[4]; } r;
        r.u = *reinterpret_cast<const uint2*>(&lg[p * LGW + m0]);
        const float e0 = __expf((float)r.h4[0] - bmax[p]);
        const float e1 = __expf((float)r.h4[1] - bmax[p]);
        const float e2 = __expf((float)r.h4[2] - bmax[p]);
        const float e3 = __expf((float)r.h4[3] - bmax[p]);
        psum[p] = (e0 + e1) + (e2 + e3);
        union { uint2 u; half_t h4[4]; } w;
        w.h4[0] = (half_t)e0; w.h4[1] = (half_t)e1;
        w.h4[2] = (half_t)e2; w.h4[3] = (half_t)e3;
        *reinterpret_cast<uint2*>(&lg[p * LGW + m0]) = w.u;
    }
#pragma unroll
    for (int p = 0; p < 8; ++p)
#pragma unroll
        for (int s = 32; s > 0; s >>= 1)
            psum[p] += __shfl_xor(psum[p], s);
    if ((tid & 63) == 0) {
#pragma unroll
        for (int p = 0; p < 8; ++p) wsum[wv][p] = psum[p];
    }
    __syncthreads();

    // ---- PV: 4 lanes share (h,vp); 2-deep prefetch on V and weights ----
    {
        const int g   = tid >> 2;          // 0..63 = h*8 + vp
        const int h   = g >> 3, vp = g & 7;
        const int sub = tid & 3;
        const unsigned int* vb = Vp + ((size_t)((b * NH + h) * 8 + vp)) * NN;
        const half_t* lrow = &lg[h * LGW];
        float a0 = 0.f, a1 = 0.f;          // v = 2vp, 2vp+1

        uint4 v0 = *reinterpret_cast<const uint4*>(vb + sub * 4);
        uint4 v1 = *reinterpret_cast<const uint4*>(vb + sub * 4 + 16);
        uint2 w0 = *reinterpret_cast<const uint2*>(lrow + sub * 4);
        uint2 w1p = *reinterpret_cast<const uint2*>(lrow + sub * 4 + 16);

#pragma unroll 2
        for (int j = 0; j < 64; ++j) {
            const uint4 vv = v0;
            const uint2 wu = w0;
            v0 = v1; w0 = w1p;
            if (j < 62) {
                const int nn2 = sub * 4 + 16 * (j + 2);
                v1  = *reinterpret_cast<const uint4*>(vb + nn2);
                w1p = *reinterpret_cast<const uint2*>(lrow + nn2);
            }
            union { uint2 u; half_t h4[4]; } wr; wr.u = wu;
            const float f0 = (float)wr.h4[0], f1 = (float)wr.h4[1];
            const float f2 = (float)wr.h4[2], f3 = (float)wr.h4[3];
            union { unsigned int u; half2_t h2; } c;
            c.u = vv.x; a0 = fmaf(f0, (float)c.h2.x, a0); a1 = fmaf(f0, (float)c.h2.y, a1);
            c.u = vv.y; a0 = fmaf(f1, (float)c.h2.x, a0); a1 = fmaf(f1, (float)c.h2.y, a1);
            c.u = vv.z; a0 = fmaf(f2, (float)c.h2.x, a0); a1 = fmaf(f2, (float)c.h2.y, a1);
            c.u = vv.w; a0 = fmaf(f3, (float)c.h2.x, a0); a1 = fmaf(f3, (float)c.h2.y, a1);
        }
        a0 += __shfl_xor(a0, 1); a0 += __shfl_xor(a0, 2);
        a1 += __shfl_xor(a1, 1); a1 += __shfl_xor(a1, 2);
        if (sub == 0) {
            const float s = (wsum[0][h] + wsum[1][h]) + (wsum[2][h] + wsum[3][h]);
            const float r = 1.0f / s;
            headsSh[h * 16 + vp * 2 + 0] = a0 * r;
            headsSh[h * 16 + vp * 2 + 1] = a1 * r;
        }
    }
    __syncthreads();

    // ---- output projection: out[b,n,e] = sum_hv heads[hv] * Wout[hv,e] ----
    {
        const int e = tid & 127, hf2 = tid >> 7;
        float a = 0.f;
#pragma unroll
        for (int hv = 0; hv < 64; ++hv) {
            const int i = hf2 * 64 + hv;
            a = fmaf(headsSh[i], Wout[(size_t)i * 128 + e], a);
        }
        float* red = reinterpret_cast<float*>(lg);
        red[tid] = a;
        __syncthreads();
        if (tid < 128)
            out[((size_t)(b * NN + n)) * 128 + tid] = red[tid] + red[tid + 128];
    }
}

extern "C" void kernel_launch(void* const* d_in, const int* in_sizes, int n_in,
                              void* d_out, int out_size, void* d_ws, size_t ws_size,
                              hipStream_t stream) {
    const float* q    = (const float*)d_in[0];
    const float* oss  = (const float*)d_in[1];
    const float* st   = (const float*)d_in[2];
    const float* Wq   = (const float*)d_in[3];
    const float* Wk   = (const float*)d_in[4];
    const float* Wv   = (const float*)d_in[5];
    const float* w1   = (const float*)d_in[6];
    const float* b1   = (const float*)d_in[7];
    const float* w2   = (const float*)d_in[8];
    const float* b2   = (const float*)d_in[9];
    const float* Wout = (const float*)d_in[10];
    float* out = (float*)d_out;

    half_t* Qh = (half_t*)d_ws;                                   // 1 MB f16
    half_t* Kp = (half_t*)((char*)d_ws + 1u * 1024u * 1024u);     // 1 MB f16 (k-pair packed)
    half_t* Vp = (half_t*)((char*)d_ws + 2u * 1024u * 1024u);     // 1 MB f16 (v-pair packed)

    qkv_kernel<<<dim3(BB * NN), dim3(128), 0, stream>>>(q, Wq, Wk, Wv, Qh, Kp, Vp);
    fused_kernel<<<dim3(NN, BB), dim3(256), 0, stream>>>(
        oss, st, Qh, (const unsigned int*)Kp, (const unsigned int*)Vp,
        w1, b1, w2, b2, Wout, out);
}